// Round 1
// baseline (7202.986 us; speedup 1.0000x reference)
//
#include <hip/hip_runtime.h>
#include <math.h>

#define SEQ   20
#define BATCH 4096
#define XDIM  752

// ---------------------------------------------------------------------------
// Generic tiled GEMM:  C[M x N] = act( A1@B1^T + A2@B2^T + bias )
//   A row-major with arbitrary row stride (lda), B row-major [N x K] with
//   arbitrary row stride (ldb).  A2/B2 optional (nullptr => skipped).
//   Three segment descriptors selected by blockIdx.z (lets one launch cover
//   the t/a/v LSTM gate GEMMs or the g1/g2 pair).
// Tile: BM=BN=64, BK=16, 256 threads, 4x4 accum per thread.
// ---------------------------------------------------------------------------
struct Seg {
  const float* A1; const float* A2;
  const float* B1; const float* B2;
  const float* bias; float* C;
  int lda1, K1, lda2, K2, ldb1, ldb2, ldc, N;
};

__device__ __forceinline__ float sigmoidf_(float x) { return 1.f / (1.f + __expf(-x)); }

template <int ACT>  // 0 none, 1 relu, 2 sigmoid, 3 tanh
__global__ __launch_bounds__(256) void gemm_dual(Seg s0, Seg s1, Seg s2) {
  Seg s = (blockIdx.z == 0) ? s0 : (blockIdx.z == 1 ? s1 : s2);
  const int bm = blockIdx.x * 64;
  const int bn = blockIdx.y * 64;
  if (bn >= s.N) return;  // uniform per block

  __shared__ float As[16][64];  // [k][m]
  __shared__ float Bs[16][64];  // [k][n]

  const int tid = threadIdx.x;
  const int tx = tid & 15, ty = tid >> 4;
  const int lm = tid >> 2;         // 0..63 : row (A) / col (B) loaded by this thread
  const int kb = (tid & 3) * 4;    // k sub-base

  float acc[4][4] = {};

  for (int part = 0; part < 2; ++part) {
    const float* A = part ? s.A2 : s.A1;
    const float* B = part ? s.B2 : s.B1;
    const int lda = part ? s.lda2 : s.lda1;
    const int ldb = part ? s.ldb2 : s.ldb1;
    const int K = part ? s.K2 : s.K1;
    if (A == nullptr || K <= 0) continue;
    const float* Arow = A + (size_t)(bm + lm) * lda;
    const float* Brow = B + (size_t)(bn + lm) * ldb;
    for (int k0 = 0; k0 < K; k0 += 16) {
#pragma unroll
      for (int j = 0; j < 4; ++j) {
        const int k = k0 + kb + j;
        As[kb + j][lm] = (k < K) ? Arow[k] : 0.f;
        Bs[kb + j][lm] = (k < K) ? Brow[k] : 0.f;
      }
      __syncthreads();
#pragma unroll
      for (int k = 0; k < 16; ++k) {
        const float4 av = *(const float4*)&As[k][ty * 4];
        const float4 bv = *(const float4*)&Bs[k][tx * 4];
        const float a0[4] = {av.x, av.y, av.z, av.w};
        const float b0[4] = {bv.x, bv.y, bv.z, bv.w};
#pragma unroll
        for (int i = 0; i < 4; ++i)
#pragma unroll
          for (int j = 0; j < 4; ++j) acc[i][j] = fmaf(a0[i], b0[j], acc[i][j]);
      }
      __syncthreads();
    }
  }

#pragma unroll
  for (int i = 0; i < 4; ++i) {
    float* crow = s.C + (size_t)(bm + ty * 4 + i) * s.ldc + bn + tx * 4;
#pragma unroll
    for (int j = 0; j < 4; ++j) {
      float v = acc[i][j] + s.bias[bn + tx * 4 + j];
      if (ACT == 1) v = fmaxf(v, 0.f);
      else if (ACT == 2) v = sigmoidf_(v);
      else if (ACT == 3) v = tanhf(v);
      crow[j] = v;
    }
  }
}

// ---------------------------------------------------------------------------
// State init: H = 0, C = [c_t | c_a | c_v], M = mem
// ---------------------------------------------------------------------------
__global__ __launch_bounds__(256) void init_state(const float* __restrict__ c_t,
                                                  const float* __restrict__ c_a,
                                                  const float* __restrict__ c_v,
                                                  const float* __restrict__ mem,
                                                  float* __restrict__ H, float* __restrict__ C,
                                                  float* __restrict__ M) {
  const int idx = blockIdx.x * 256 + threadIdx.x;  // BATCH*256
  const int row = idx >> 8, j = idx & 255;
  H[idx] = 0.f;
  float c;
  if (j < 128) c = c_t[row * 128 + j];
  else if (j < 192) c = c_a[row * 64 + (j - 128)];
  else c = c_v[row * 64 + (j - 192)];
  C[idx] = c;
  M[idx] = mem[idx];
}

// ---------------------------------------------------------------------------
// LSTM pointwise update for all three cells.
// zg row layout: [t: i f g o (128 each) | a: i f g o (64 each) | v: i f g o]
// Also emits c_star = [old C | new C].
// ---------------------------------------------------------------------------
__global__ __launch_bounds__(256) void lstm_update(const float* __restrict__ zg,
                                                   float* __restrict__ H, float* __restrict__ C,
                                                   float* __restrict__ cstar) {
  const int idx = blockIdx.x * 256 + threadIdx.x;  // BATCH*256
  const int row = idx >> 8, j = idx & 255;
  int zb, u, hsz;
  if (j < 128) { zb = 0; u = j; hsz = 128; }
  else if (j < 192) { zb = 512; u = j - 128; hsz = 64; }
  else { zb = 768; u = j - 192; hsz = 64; }
  const float* z = zg + (size_t)row * 1024 + zb;
  const float gi = sigmoidf_(z[u]);
  const float gf = sigmoidf_(z[u + hsz]);
  const float gg = tanhf(z[u + 2 * hsz]);
  const float go = sigmoidf_(z[u + 3 * hsz]);
  const float cold = C[idx];
  const float cnew = gf * cold + gi * gg;
  const float h = go * tanhf(cnew);
  cstar[(size_t)row * 512 + j] = cold;
  cstar[(size_t)row * 512 + 256 + j] = cnew;
  C[idx] = cnew;
  H[idx] = h;
}

// ---------------------------------------------------------------------------
// Row softmax over 512 logits, then cstar *= softmax (in place -> attended).
// One wave per row.
// ---------------------------------------------------------------------------
__global__ __launch_bounds__(256) void softmax_mul(const float* __restrict__ logits,
                                                   float* __restrict__ cstar) {
  const int gid = blockIdx.x * 4 + (threadIdx.x >> 6);
  const int lane = threadIdx.x & 63;
  const float* L = logits + (size_t)gid * 512;
  float* Cs = cstar + (size_t)gid * 512;
  float v[8];
  float mx = -1e30f;
#pragma unroll
  for (int j = 0; j < 8; ++j) { v[j] = L[lane + j * 64]; mx = fmaxf(mx, v[j]); }
#pragma unroll
  for (int o = 1; o < 64; o <<= 1) mx = fmaxf(mx, __shfl_xor(mx, o));
  float sum = 0.f;
#pragma unroll
  for (int j = 0; j < 8; ++j) { v[j] = __expf(v[j] - mx); sum += v[j]; }
#pragma unroll
  for (int o = 1; o < 64; o <<= 1) sum += __shfl_xor(sum, o);
  const float inv = 1.f / sum;
#pragma unroll
  for (int j = 0; j < 8; ++j) Cs[lane + j * 64] *= v[j] * inv;
}

// ---------------------------------------------------------------------------
// Memory update: M = g1 * M + g2 * chat   (g1/g2 already sigmoided, chat tanh'd)
// ---------------------------------------------------------------------------
__global__ __launch_bounds__(256) void m_update(const float* __restrict__ g1o,
                                                const float* __restrict__ g2o,
                                                const float* __restrict__ chat,
                                                float* __restrict__ M) {
  const int idx = blockIdx.x * 256 + threadIdx.x;
  M[idx] = g1o[idx] * M[idx] + g2o[idx] * chat[idx];
}

// ---------------------------------------------------------------------------
// Output head second layer: out[r] = dot(hid[r][0:128], W2) + b2. One wave/row.
// ---------------------------------------------------------------------------
__global__ __launch_bounds__(256) void out_head(const float* __restrict__ hid,
                                                const float* __restrict__ W2,
                                                const float* __restrict__ b2,
                                                float* __restrict__ out) {
  const int gid = blockIdx.x * 4 + (threadIdx.x >> 6);
  const int lane = threadIdx.x & 63;
  const float* h = hid + (size_t)gid * 256;
  float s = h[lane] * W2[lane] + h[64 + lane] * W2[64 + lane];
#pragma unroll
  for (int o = 1; o < 64; o <<= 1) s += __shfl_xor(s, o);
  if (lane == 0) out[gid] = s + b2[0];
}

// ---------------------------------------------------------------------------
extern "C" void kernel_launch(void* const* d_in, const int* in_sizes, int n_in,
                              void* d_out, int out_size, void* d_ws, size_t ws_size,
                              hipStream_t stream) {
  (void)in_sizes; (void)n_in; (void)out_size; (void)ws_size;
  const float* x_p = (const float*)d_in[0];
  const float* c_t = (const float*)d_in[1];
  const float* c_a = (const float*)d_in[2];
  const float* c_v = (const float*)d_in[3];
  const float* mem0 = (const float*)d_in[4];
  const float* t_Wih = (const float*)d_in[5];
  const float* t_Whh = (const float*)d_in[6];
  const float* t_b = (const float*)d_in[7];
  const float* a_Wih = (const float*)d_in[8];
  const float* a_Whh = (const float*)d_in[9];
  const float* a_b = (const float*)d_in[10];
  const float* v_Wih = (const float*)d_in[11];
  const float* v_Whh = (const float*)d_in[12];
  const float* v_b = (const float*)d_in[13];
  const float* attn1_W1 = (const float*)d_in[14];
  const float* attn1_b1 = (const float*)d_in[15];
  const float* attn1_W2 = (const float*)d_in[16];
  const float* attn1_b2 = (const float*)d_in[17];
  const float* attn2_W1 = (const float*)d_in[18];
  const float* attn2_b1 = (const float*)d_in[19];
  const float* attn2_W2 = (const float*)d_in[20];
  const float* attn2_b2 = (const float*)d_in[21];
  const float* g1_W1 = (const float*)d_in[22];
  const float* g1_b1 = (const float*)d_in[23];
  const float* g1_W2 = (const float*)d_in[24];
  const float* g1_b2 = (const float*)d_in[25];
  const float* g2_W1 = (const float*)d_in[26];
  const float* g2_b1 = (const float*)d_in[27];
  const float* g2_W2 = (const float*)d_in[28];
  const float* g2_b2 = (const float*)d_in[29];
  const float* out_W1 = (const float*)d_in[30];
  const float* out_b1 = (const float*)d_in[31];
  const float* out_W2 = (const float*)d_in[32];
  const float* out_b2 = (const float*)d_in[33];

  float* ws = (float*)d_ws;
  const size_t R = BATCH;
  float* H = ws;               // [R x 256]  (t_h | a_h | v_h)
  float* C = H + R * 256;      // [R x 256]  (t_c | a_c | v_c)
  float* Mst = C + R * 256;    // [R x 256]
  float* zg = Mst + R * 256;   // [R x 1024] gate pre-activations
  float* cst = zg + R * 1024;  // [R x 512]  c_star -> attended (in place)
  float* hid = cst + R * 512;  // [R x 256]  MLP hidden (attn: first 128; g1|g2: 128+128)
  float* aou = hid + R * 256;  // [R x 512]  attn1 logits
  float* cht = aou + R * 512;  // [R x 256]  c_hat
  float* g1o = cht + R * 256;  // [R x 256]
  float* g2o = g1o + R * 256;  // [R x 256]

  init_state<<<R, 256, 0, stream>>>(c_t, c_a, c_v, mem0, H, C, Mst);

  for (int t = 0; t < SEQ; ++t) {
    const float* xt = x_p + (size_t)t * R * XDIM;
    // gates: z = x_slice @ Wih^T + h_slice @ Whh^T + b   (3 segments: t,a,v)
    Seg st{xt, H, t_Wih, t_Whh, t_b, zg, 752, 300, 256, 128, 300, 128, 1024, 512};
    Seg sa{xt + 300, H + 128, a_Wih, a_Whh, a_b, zg + 512, 752, 81, 256, 64, 81, 64, 1024, 256};
    Seg sv{xt + 381, H + 192, v_Wih, v_Whh, v_b, zg + 768, 752, 371, 256, 64, 371, 64, 1024, 256};
    gemm_dual<0><<<dim3(64, 8, 3), 256, 0, stream>>>(st, sa, sv);
    lstm_update<<<R, 256, 0, stream>>>(zg, H, C, cst);

    // attn1 MLP -> logits; softmax * c_star (in place)
    Seg a11{cst, nullptr, attn1_W1, nullptr, attn1_b1, hid, 512, 512, 0, 0, 512, 0, 256, 128};
    gemm_dual<1><<<dim3(64, 2, 1), 256, 0, stream>>>(a11, a11, a11);
    Seg a12{hid, nullptr, attn1_W2, nullptr, attn1_b2, aou, 256, 128, 0, 0, 128, 0, 512, 512};
    gemm_dual<0><<<dim3(64, 8, 1), 256, 0, stream>>>(a12, a12, a12);
    softmax_mul<<<R / 4, 256, 0, stream>>>(aou, cst);

    // attn2 MLP -> c_hat = tanh(...)
    Seg a21{cst, nullptr, attn2_W1, nullptr, attn2_b1, hid, 512, 512, 0, 0, 512, 0, 256, 128};
    gemm_dual<1><<<dim3(64, 2, 1), 256, 0, stream>>>(a21, a21, a21);
    Seg a22{hid, nullptr, attn2_W2, nullptr, attn2_b2, cht, 256, 128, 0, 0, 128, 0, 256, 256};
    gemm_dual<3><<<dim3(64, 4, 1), 256, 0, stream>>>(a22, a22, a22);

    // g1/g2 hidden: both = [attended | M]  (dual-A, W1 split at column 512)
    Seg gh1{cst, Mst, g1_W1, g1_W1 + 512, g1_b1, hid, 512, 512, 256, 256, 768, 768, 256, 128};
    Seg gh2{cst, Mst, g2_W1, g2_W1 + 512, g2_b1, hid + 128, 512, 512, 256, 256, 768, 768, 256, 128};
    gemm_dual<1><<<dim3(64, 2, 2), 256, 0, stream>>>(gh1, gh2, gh2);
    // g1/g2 second layer, sigmoid
    Seg go1{hid, nullptr, g1_W2, nullptr, g1_b2, g1o, 256, 128, 0, 0, 128, 0, 256, 256};
    Seg go2{hid + 128, nullptr, g2_W2, nullptr, g2_b2, g2o, 256, 128, 0, 0, 128, 0, 256, 256};
    gemm_dual<2><<<dim3(64, 4, 2), 256, 0, stream>>>(go1, go2, go2);
    m_update<<<R, 256, 0, stream>>>(g1o, g2o, cht, Mst);
  }

  // output head: relu([H | M] @ out_W1^T + b1) @ out_W2^T + b2
  Seg oh{H, Mst, out_W1, out_W1 + 256, out_b1, hid, 256, 256, 256, 256, 512, 512, 256, 128};
  gemm_dual<1><<<dim3(64, 2, 1), 256, 0, stream>>>(oh, oh, oh);
  out_head<<<R / 4, 256, 0, stream>>>(hid, out_W2, out_b2, (float*)d_out);
}

// Round 2
// 1381.984 us; speedup vs baseline: 5.2121x; 5.2121x over previous
//
#include <hip/hip_runtime.h>
#include <math.h>

typedef _Float16 f16;
typedef f16 f16x8 __attribute__((ext_vector_type(8)));
typedef float f32x4 __attribute__((ext_vector_type(4)));

#define MFMA16(a, b, c) __builtin_amdgcn_mfma_f32_16x16x32_f16((a), (b), (c), 0, 0, 0)

// ---------------------------------------------------------------------------
// ws layout (bytes):
//  Wg_t  fp16 [512][448]  @ 0        (gates t: cols 0:300 Wih, 320:448 Whh, rows interleaved n=4u+g)
//  Wg_a  fp16 [256][160]  @ 458752   (cols 0:81 Wih, 96:160 Whh)
//  Wg_v  fp16 [256][448]  @ 540672   (cols 0:371 Wih, 384:448 Whh)
//  W_a1  fp16 [128][512]  @ 770048   attn1_W1
//  W_a2  fp16 [512][128]  @ 901120   attn1_W2
//  W_b1  fp16 [128][512]  @ 1032192  attn2_W1
//  W_b2  fp16 [256][128]  @ 1163264  attn2_W2
//  W_g1  fp16 [256][768]  @ 1228800  rows 0:128 g1_W1, 128:256 g2_W1
//  W_g2  fp16 [512][128]  @ 1622016  rows 0:256 g1_W2, 256:512 g2_W2
//  W_o1  fp16 [128][512]  @ 1753088  out_W1
//  bg    f32  [1024]      @ 1884160  gate bias, interleaved layout
// ---------------------------------------------------------------------------

struct PackArgs {
  const float *t_Wih, *t_Whh, *t_b, *a_Wih, *a_Whh, *a_b, *v_Wih, *v_Whh, *v_b;
  const float *aW1, *aW2, *bW1, *bW2, *g1W1, *g2W1, *g1W2, *g2W2, *oW1;
  f16 *Wg_t, *Wg_a, *Wg_v, *W_a1, *W_a2, *W_b1, *W_b2, *W_g1, *W_g2, *W_o1;
  float *bg;
};

__global__ __launch_bounds__(256) void pack_w(PackArgs p) {
  int idx = blockIdx.x * 256 + threadIdx.x;
  if (idx < 229376) {  // Wg_t [512][448]
    int n = idx / 448, k = idx % 448;
    int srow = (n & 3) * 128 + (n >> 2);
    float v = (k < 300) ? p.t_Wih[srow * 300 + k]
                        : ((k >= 320) ? p.t_Whh[srow * 128 + k - 320] : 0.f);
    p.Wg_t[idx] = (f16)v; return;
  }
  idx -= 229376;
  if (idx < 40960) {  // Wg_a [256][160]
    int n = idx / 160, k = idx % 160;
    int srow = (n & 3) * 64 + (n >> 2);
    float v = (k < 81) ? p.a_Wih[srow * 81 + k]
                       : ((k >= 96) ? p.a_Whh[srow * 64 + k - 96] : 0.f);
    p.Wg_a[idx] = (f16)v; return;
  }
  idx -= 40960;
  if (idx < 114688) {  // Wg_v [256][448]
    int n = idx / 448, k = idx % 448;
    int srow = (n & 3) * 64 + (n >> 2);
    float v = (k < 371) ? p.v_Wih[srow * 371 + k]
                        : ((k >= 384) ? p.v_Whh[srow * 64 + k - 384] : 0.f);
    p.Wg_v[idx] = (f16)v; return;
  }
  idx -= 114688;
  if (idx < 65536) { p.W_a1[idx] = (f16)p.aW1[idx]; return; }
  idx -= 65536;
  if (idx < 65536) { p.W_a2[idx] = (f16)p.aW2[idx]; return; }
  idx -= 65536;
  if (idx < 65536) { p.W_b1[idx] = (f16)p.bW1[idx]; return; }
  idx -= 65536;
  if (idx < 32768) { p.W_b2[idx] = (f16)p.bW2[idx]; return; }
  idx -= 32768;
  if (idx < 196608) {  // W_g1 [256][768]
    int n = idx / 768;
    p.W_g1[idx] = (f16)((n < 128) ? p.g1W1[idx] : p.g2W1[idx - 98304]);
    return;
  }
  idx -= 196608;
  if (idx < 65536) {  // W_g2 [512][128]
    int n = idx / 128;
    p.W_g2[idx] = (f16)((n < 256) ? p.g1W2[idx] : p.g2W2[idx - 32768]);
    return;
  }
  idx -= 65536;
  if (idx < 65536) { p.W_o1[idx] = (f16)p.oW1[idx]; return; }
  idx -= 65536;
  if (idx < 1024) {  // bg
    int n = idx;
    float v;
    if (n < 512)      v = p.t_b[(n & 3) * 128 + (n >> 2)];
    else if (n < 768) { int m = n - 512; v = p.a_b[(m & 3) * 64 + (m >> 2)]; }
    else              { int m = n - 768; v = p.v_b[(m & 3) * 64 + (m >> 2)]; }
    p.bg[n] = v;
  }
}

struct MainArgs {
  const float *x_p, *c_t, *c_a, *c_v, *mem0;
  const f16 *Wg_t, *Wg_a, *Wg_v, *W_a1, *W_a2, *W_b1, *W_b2, *W_g1, *W_g2, *W_o1;
  const float *bg, *a1b1, *a1b2, *a2b1, *a2b2, *g1b1, *g1b2, *g2b1, *g2b2, *ob1, *oW2, *ob2;
  float *out;
};

// K-dot helper: A frag base advances 32 fp16/kstep, W row base likewise.
template <int KS>
__device__ __forceinline__ f32x4 dot16(const f16* Ab, const f16* Wb) {
  f32x4 acc = {0.f, 0.f, 0.f, 0.f};
#pragma unroll
  for (int ks = 0; ks < KS; ++ks)
    acc = MFMA16(*(const f16x8*)(Ab + 32 * ks), *(const f16x8*)(Wb + 32 * ks), acc);
  return acc;
}

__device__ __forceinline__ float sigm(float x) { return 1.f / (1.f + __expf(-x)); }

__global__ __launch_bounds__(512, 2) void fused_seq(MainArgs A) {
  // LDS: 134,400 B total (< 160 KiB)
  __shared__ f16  h16[16][264];     // current h (fp16, GEMM A-source)
  __shared__ float cS[16][260];     // cell state f32
  __shared__ float mS[16][260];     // memory f32
  __shared__ f16  bufA[16][808];    // cstar/attended (0:512) | m fp16 (512:768)
  __shared__ f16  hid16[16][264];   // MLP hidden (attn1/attn2/out)
  __shared__ f16  ghid16[16][264];  // g1|g2 hidden
  __shared__ float zf[16][520];     // logits (0:512), then g1o|g2o (0:512)
  __shared__ float chat[16][260];   // c_hat f32

  const int tid = threadIdx.x;
  const int wid = tid >> 6, lane = tid & 63, l15 = lane & 15, lg = lane >> 4;
  const int r0 = blockIdx.x * 16;

  // ---- init state ----
  for (int idx = tid; idx < 4096; idx += 512) {
    int r = idx >> 8, c = idx & 255, R = r0 + r;
    h16[r][c] = (f16)0.f;
    float cv = (c < 128) ? A.c_t[R * 128 + c]
                         : (c < 192 ? A.c_a[R * 64 + c - 128] : A.c_v[R * 64 + c - 192]);
    cS[r][c] = cv;
    mS[r][c] = A.mem0[R * 256 + c];
  }
  __syncthreads();

  // ---- wave-uniform gate-stage parameters ----
  int KSXr, KXRr, KSHr, xb, hb, cub, nc0, n0, Kp;
  const f16* Wc;
  if (wid < 4)      { KSXr = 10; KXRr = 300; KSHr = 4; xb = 0;   hb = 0;   cub = 0;   nc0 = 128 * wid;       n0 = nc0;       Wc = A.Wg_t; Kp = 448; }
  else if (wid < 6) { KSXr = 3;  KXRr = 81;  KSHr = 2; xb = 300; hb = 128; cub = 128; nc0 = 128 * (wid - 4); n0 = 512 + nc0; Wc = A.Wg_a; Kp = 160; }
  else              { KSXr = 12; KXRr = 371; KSHr = 2; xb = 381; hb = 192; cub = 192; nc0 = 128 * (wid - 6); n0 = 768 + nc0; Wc = A.Wg_v; Kp = 448; }

  for (int t = 0; t < 20; ++t) {
    // ================= STAGE G: LSTM gates (MFMA) + pointwise =================
    const float* xrow = A.x_p + ((size_t)t * 4096 + r0 + l15) * 752 + xb;
    f16x8 ax[12]; f16x8 ah[4];
#pragma unroll
    for (int ks = 0; ks < 12; ++ks) if (ks < KSXr) {
      int kk = 32 * ks + 8 * lg;
      float t0[8];
      if (kk + 8 <= KXRr) {
        float4 p0 = *(const float4*)(xrow + kk);
        float4 p1 = *(const float4*)(xrow + kk + 4);
        t0[0] = p0.x; t0[1] = p0.y; t0[2] = p0.z; t0[3] = p0.w;
        t0[4] = p1.x; t0[5] = p1.y; t0[6] = p1.z; t0[7] = p1.w;
      } else {
#pragma unroll
        for (int j = 0; j < 8; ++j) t0[j] = (kk + j < KXRr) ? xrow[kk + j] : 0.f;
      }
      f16x8 vv;
#pragma unroll
      for (int j = 0; j < 8; ++j) vv[j] = (f16)t0[j];
      ax[ks] = vv;
    }
#pragma unroll
    for (int ks = 0; ks < 4; ++ks) if (ks < KSHr)
      ah[ks] = *(const f16x8*)(&h16[l15][hb + 8 * lg + 32 * ks]);
    __syncthreads();  // all waves' x/h frags in regs before h16/bufA writes

    for (int i = 0; i < 8; ++i) {
      f32x4 acc = {0.f, 0.f, 0.f, 0.f};
      const f16* wrow = Wc + (size_t)(nc0 + 16 * i + l15) * Kp + 8 * lg;
#pragma unroll
      for (int ks = 0; ks < 12; ++ks)
        if (ks < KSXr) acc = MFMA16(ax[ks], *(const f16x8*)(wrow + 32 * ks), acc);
#pragma unroll
      for (int ks = 0; ks < 4; ++ks)
        if (ks < KSHr) acc = MFMA16(ah[ks], *(const f16x8*)(wrow + 32 * (KSXr + ks)), acc);
      // epilogue: bias, activations, cross-lane LSTM update (n = 4u + gate)
      float bias = A.bg[n0 + 16 * i + l15];
      int gidx = lane & 3;
#pragma unroll
      for (int q = 0; q < 4; ++q) {
        float z = acc[q] + bias;
        float v = (gidx == 2) ? tanhf(z) : sigm(z);
        float vf = __shfl_xor(v, 1);
        float vg = __shfl_xor(v, 2);
        float vo = __shfl_xor(v, 3);
        if ((lane & 3) == 0) {  // v=sig(i), vf=sig(f), vg=tanh(g), vo=sig(o)
          int u = (nc0 + 16 * i + l15) >> 2;
          int cu = cub + u;
          int row = lg * 4 + q;
          float cold = cS[row][cu];
          float cnew = vf * cold + v * vg;
          cS[row][cu] = cnew;
          h16[row][cu] = (f16)(vo * tanhf(cnew));
          bufA[row][cu] = (f16)cold;        // c_star = [pre_c | cur_c]
          bufA[row][256 + cu] = (f16)cnew;
        }
      }
    }
    __syncthreads();

    // ================= attn1 L1: hid = relu(cstar @ W^T + b), N=128 K=512 ====
    {
      const f16* Ab = &bufA[l15][8 * lg];
      int n = 16 * wid;
      f32x4 acc = dot16<16>(Ab, A.W_a1 + (size_t)(n + l15) * 512 + 8 * lg);
      float b = A.a1b1[n + l15];
#pragma unroll
      for (int q = 0; q < 4; ++q) hid16[lg * 4 + q][n + l15] = (f16)fmaxf(acc[q] + b, 0.f);
    }
    __syncthreads();

    // ================= attn1 L2: logits = hid @ W^T + b, N=512 K=128 =========
    {
      const f16* Ab = &hid16[l15][8 * lg];
#pragma unroll
      for (int i = 0; i < 4; ++i) {
        int n = 64 * wid + 16 * i;
        f32x4 acc = dot16<4>(Ab, A.W_a2 + (size_t)(n + l15) * 128 + 8 * lg);
        float b = A.a1b2[n + l15];
#pragma unroll
        for (int q = 0; q < 4; ++q) zf[lg * 4 + q][n + l15] = acc[q] + b;
      }
    }
    __syncthreads();

    // ================= softmax * cstar (in place), m -> bufA[512:768] ========
    {
      int row = tid >> 5, c0 = tid & 31;
      float v[16]; float mx = -1e30f;
#pragma unroll
      for (int j = 0; j < 16; ++j) { v[j] = zf[row][c0 + 32 * j]; mx = fmaxf(mx, v[j]); }
#pragma unroll
      for (int m = 1; m < 32; m <<= 1) mx = fmaxf(mx, __shfl_xor(mx, m));
      float s = 0.f;
#pragma unroll
      for (int j = 0; j < 16; ++j) { v[j] = __expf(v[j] - mx); s += v[j]; }
#pragma unroll
      for (int m = 1; m < 32; m <<= 1) s += __shfl_xor(s, m);
      float inv = 1.f / s;
#pragma unroll
      for (int j = 0; j < 16; ++j) {
        int c = c0 + 32 * j;
        bufA[row][c] = (f16)(v[j] * inv * (float)bufA[row][c]);
      }
      for (int idx = tid; idx < 4096; idx += 512) {
        int r = idx >> 8, c = idx & 255;
        bufA[r][512 + c] = (f16)mS[r][c];
      }
    }
    __syncthreads();

    // ================= attn2 L1: hid2 = relu(attended @ W^T + b) =============
    {
      const f16* Ab = &bufA[l15][8 * lg];
      int n = 16 * wid;
      f32x4 acc = dot16<16>(Ab, A.W_b1 + (size_t)(n + l15) * 512 + 8 * lg);
      float b = A.a2b1[n + l15];
#pragma unroll
      for (int q = 0; q < 4; ++q) hid16[lg * 4 + q][n + l15] = (f16)fmaxf(acc[q] + b, 0.f);
    }
    __syncthreads();

    // ====== attn2 L2 (waves 6,7) || g-hidden (waves 0-5, K=768 from bufA) ====
    if (wid >= 6) {
      const f16* Ab = &hid16[l15][8 * lg];
#pragma unroll
      for (int i = 0; i < 8; ++i) {
        int n = 128 * (wid - 6) + 16 * i;
        f32x4 acc = dot16<4>(Ab, A.W_b2 + (size_t)(n + l15) * 128 + 8 * lg);
        float b = A.a2b2[n + l15];
#pragma unroll
        for (int q = 0; q < 4; ++q) chat[lg * 4 + q][n + l15] = tanhf(acc[q] + b);
      }
    } else {
      const f16* Ab = &bufA[l15][8 * lg];
      int start = (wid < 4) ? 3 * wid : 12 + 2 * (wid - 4);
      int cnt = (wid < 4) ? 3 : 2;
#pragma unroll
      for (int i = 0; i < 3; ++i) if (i < cnt) {
        int n = 16 * (start + i);
        f32x4 acc = dot16<24>(Ab, A.W_g1 + (size_t)(n + l15) * 768 + 8 * lg);
        float b = (n + l15 < 128) ? A.g1b1[n + l15] : A.g2b1[n + l15 - 128];
#pragma unroll
        for (int q = 0; q < 4; ++q) ghid16[lg * 4 + q][n + l15] = (f16)fmaxf(acc[q] + b, 0.f);
      }
    }
    __syncthreads();

    // ================= g second layers -> zf = [g1o | g2o] ===================
    {
      int isg2 = (wid >= 4);
      const f16* Ab = &ghid16[l15][(isg2 ? 128 : 0) + 8 * lg];
      int w4 = isg2 ? (wid - 4) : wid;
#pragma unroll
      for (int i = 0; i < 4; ++i) {
        int n = 64 * w4 + 16 * i;
        f32x4 acc = dot16<4>(Ab, A.W_g2 + (size_t)((isg2 ? 256 : 0) + n + l15) * 128 + 8 * lg);
        float b = isg2 ? A.g2b2[n + l15] : A.g1b2[n + l15];
        int zc = (isg2 ? 256 : 0) + n + l15;
#pragma unroll
        for (int q = 0; q < 4; ++q) zf[lg * 4 + q][zc] = sigm(acc[q] + b);
      }
    }
    __syncthreads();

    // ================= memory update =========================================
    for (int idx = tid; idx < 4096; idx += 512) {
      int r = idx >> 8, c = idx & 255;
      mS[r][c] = zf[r][c] * mS[r][c] + zf[r][256 + c] * chat[r][c];
    }
    __syncthreads();
  }

  // ================= output head ============================================
  for (int idx = tid; idx < 4096; idx += 512) {
    int r = idx >> 8, c = idx & 255;
    bufA[r][c] = h16[r][c];
    bufA[r][256 + c] = (f16)mS[r][c];
  }
  __syncthreads();
  {
    const f16* Ab = &bufA[l15][8 * lg];
    int n = 16 * wid;
    f32x4 acc = dot16<16>(Ab, A.W_o1 + (size_t)(n + l15) * 512 + 8 * lg);
    float b = A.ob1[n + l15];
#pragma unroll
    for (int q = 0; q < 4; ++q) hid16[lg * 4 + q][n + l15] = (f16)fmaxf(acc[q] + b, 0.f);
  }
  __syncthreads();
  {
    int row = tid >> 5, c0 = tid & 31;
    float s = 0.f;
#pragma unroll
    for (int j = 0; j < 4; ++j) { int k = c0 + 32 * j; s += (float)hid16[row][k] * A.oW2[k]; }
#pragma unroll
    for (int m = 1; m < 32; m <<= 1) s += __shfl_xor(s, m);
    if (c0 == 0) A.out[r0 + row] = s + A.ob2[0];
  }
}

extern "C" void kernel_launch(void* const* d_in, const int* in_sizes, int n_in,
                              void* d_out, int out_size, void* d_ws, size_t ws_size,
                              hipStream_t stream) {
  (void)in_sizes; (void)n_in; (void)out_size; (void)ws_size;
  char* w = (char*)d_ws;
  f16* Wg_t = (f16*)(w + 0);
  f16* Wg_a = (f16*)(w + 458752);
  f16* Wg_v = (f16*)(w + 540672);
  f16* W_a1 = (f16*)(w + 770048);
  f16* W_a2 = (f16*)(w + 901120);
  f16* W_b1 = (f16*)(w + 1032192);
  f16* W_b2 = (f16*)(w + 1163264);
  f16* W_g1 = (f16*)(w + 1228800);
  f16* W_g2 = (f16*)(w + 1622016);
  f16* W_o1 = (f16*)(w + 1753088);
  float* bg = (float*)(w + 1884160);

  PackArgs pa;
  pa.t_Wih = (const float*)d_in[5];  pa.t_Whh = (const float*)d_in[6];  pa.t_b = (const float*)d_in[7];
  pa.a_Wih = (const float*)d_in[8];  pa.a_Whh = (const float*)d_in[9];  pa.a_b = (const float*)d_in[10];
  pa.v_Wih = (const float*)d_in[11]; pa.v_Whh = (const float*)d_in[12]; pa.v_b = (const float*)d_in[13];
  pa.aW1 = (const float*)d_in[14];  pa.aW2 = (const float*)d_in[16];
  pa.bW1 = (const float*)d_in[18];  pa.bW2 = (const float*)d_in[20];
  pa.g1W1 = (const float*)d_in[22]; pa.g2W1 = (const float*)d_in[26];
  pa.g1W2 = (const float*)d_in[24]; pa.g2W2 = (const float*)d_in[28];
  pa.oW1 = (const float*)d_in[30];
  pa.Wg_t = Wg_t; pa.Wg_a = Wg_a; pa.Wg_v = Wg_v; pa.W_a1 = W_a1; pa.W_a2 = W_a2;
  pa.W_b1 = W_b1; pa.W_b2 = W_b2; pa.W_g1 = W_g1; pa.W_g2 = W_g2; pa.W_o1 = W_o1;
  pa.bg = bg;
  pack_w<<<3684, 256, 0, stream>>>(pa);

  MainArgs ma;
  ma.x_p = (const float*)d_in[0];
  ma.c_t = (const float*)d_in[1]; ma.c_a = (const float*)d_in[2]; ma.c_v = (const float*)d_in[3];
  ma.mem0 = (const float*)d_in[4];
  ma.Wg_t = Wg_t; ma.Wg_a = Wg_a; ma.Wg_v = Wg_v; ma.W_a1 = W_a1; ma.W_a2 = W_a2;
  ma.W_b1 = W_b1; ma.W_b2 = W_b2; ma.W_g1 = W_g1; ma.W_g2 = W_g2; ma.W_o1 = W_o1;
  ma.bg = bg;
  ma.a1b1 = (const float*)d_in[15]; ma.a1b2 = (const float*)d_in[17];
  ma.a2b1 = (const float*)d_in[19]; ma.a2b2 = (const float*)d_in[21];
  ma.g1b1 = (const float*)d_in[23]; ma.g1b2 = (const float*)d_in[25];
  ma.g2b1 = (const float*)d_in[27]; ma.g2b2 = (const float*)d_in[29];
  ma.ob1 = (const float*)d_in[31]; ma.oW2 = (const float*)d_in[32]; ma.ob2 = (const float*)d_in[33];
  ma.out = (float*)d_out;
  fused_seq<<<256, 512, 0, stream>>>(ma);
}